// Round 7
// baseline (469.417 us; speedup 1.0000x reference)
//
#include <hip/hip_runtime.h>
#include <hip/hip_bf16.h>

// GCN over Block-CSR adjacency. ALL I/O BUFFERS ARE FLOAT32. bf16 MFMA, fp32 accum.
//
// Round 7: FUSION. R5/R6 both plateau spmm_ln at ~95us / 3.8 TB/s / 290 MB fetch
// => traffic-bound, not schedule-bound. Eliminate the h round-trip (67 MB write +
// 67 MB read per middle layer) by fusing the following GEMM into the spmm+LN
// kernel via an 8.5 KB LDS tile (C-layout -> A-layout transform). Pipeline:
//   gemm0 -> fused<256>(spmm+bias+relu+LN+ @W1) -> fused<64>(... @W2) -> spmm_out
// ws halves ping-pong: zbt1(h1) -> zbt2(h2) -> zbt3(h1, 16.8MB).
// sched_barrier(0) between gather cluster and MFMA cluster (R5/R6 evidence:
// compiler register-minimizes and sinks loads; force them outstanding).

typedef __bf16 bf16;
typedef bf16 bf16x8 __attribute__((ext_vector_type(8)));
typedef bf16 bf16x4 __attribute__((ext_vector_type(4)));
typedef float f32x4 __attribute__((ext_vector_type(4)));

#define N_NODES 131072
#define BRQ 8192      // block rows (= N/16)
#define KNZ 8         // nonzero blocks per block row
#define IN_F 128
#define HID 256
#define NCLS 64

static __device__ __forceinline__ f32x4 mfma16(bf16x8 a, bf16x8 b, f32x4 c) {
  return __builtin_amdgcn_mfma_f32_16x16x32_bf16(a, b, c, 0, 0, 0);
}

static __device__ __forceinline__ bf16x8 load8(const bf16* p) {
  return *(const bf16x8*)p;
}
static __device__ __forceinline__ bf16x8 load8(const float* p) {
  f32x4 a0 = *(const f32x4*)p;
  f32x4 a1 = *(const f32x4*)(p + 4);
  bf16x8 r;
  r[0] = (bf16)a0[0]; r[1] = (bf16)a0[1]; r[2] = (bf16)a0[2]; r[3] = (bf16)a0[3];
  r[4] = (bf16)a1[0]; r[5] = (bf16)a1[1]; r[6] = (bf16)a1[2]; r[7] = (bf16)a1[3];
  return r;
}

// ---------------- fused transpose + f32->bf16 convert for all 3 W matrices -------
__global__ void transpose_all(const float* __restrict__ W0, const float* __restrict__ W1,
                              const float* __restrict__ W2, bf16* __restrict__ w0t,
                              bf16* __restrict__ w1t, bf16* __restrict__ w2t) {
  int idx = blockIdx.x * 256 + threadIdx.x;
  if (idx < 32768) {
    int r = idx >> 8, c = idx & 255;            // 128 x 256
    w0t[c * 128 + r] = (bf16)W0[idx];
  } else if (idx < 98304) {
    int j = idx - 32768; int r = j >> 8, c = j & 255;  // 256 x 256
    w1t[c * 256 + r] = (bf16)W1[j];
  } else {
    int j = idx - 98304; int r = j >> 6, c = j & 63;   // 256 x 64
    w2t[c * 256 + r] = (bf16)W2[j];
  }
}

// ---------------- dense GEMM0: B-stationary registers -----------------------------
// Zbt[rt][col][r] = X[N,KIN] @ W; WT = W^T [FOUT,KIN] bf16 row-major.
template<typename TA, int KIN, int FOUT, int GRID>
__global__ __launch_bounds__(256) void gemm_bt(const TA* __restrict__ X,
                                               const bf16* __restrict__ WT,
                                               bf16* __restrict__ Zbt) {
  constexpr int CG  = FOUT / 64;
  constexpr int KS  = KIN / 32;
  constexpr int RTS = GRID * 4 / CG;
  constexpr int NT  = BRQ / RTS;

  const int wave = threadIdx.x >> 6;
  const int lane = threadIdx.x & 63;
  const int l15  = lane & 15;
  const int quad = lane >> 4;
  const int gw   = blockIdx.x * 4 + wave;
  const int cg   = gw % CG;
  const int rt0  = gw / CG;

  const bf16* __restrict__ wbase = WT + (long)(cg * 64 + l15) * KIN + quad * 8;
  bf16x8 bfr[KS][4];
#pragma unroll
  for (int k = 0; k < KS; ++k)
#pragma unroll
    for (int t = 0; t < 4; ++t)
      bfr[k][t] = *(const bf16x8*)(wbase + t * (16 * KIN) + k * 32);

  const TA* __restrict__ xbase = X + (long)l15 * KIN + quad * 8;

  bf16x8 aw[2][KS];
#pragma unroll
  for (int k = 0; k < KS; ++k)
    aw[0][k] = load8(xbase + (long)rt0 * (16 * KIN) + k * 32);

#pragma unroll
  for (int it = 0; it < NT; ++it) {
    const int rt = rt0 + it * RTS;
    if (it + 1 < NT) {
      const long xoff = (long)(rt + RTS) * (16 * KIN);
#pragma unroll
      for (int k = 0; k < KS; ++k)
        aw[(it + 1) & 1][k] = load8(xbase + xoff + k * 32);
    }
    f32x4 acc[4] = {};
#pragma unroll
    for (int k = 0; k < KS; ++k)
#pragma unroll
      for (int t = 0; t < 4; ++t)
        acc[t] = mfma16(aw[it & 1][k], bfr[k][t], acc[t]);
#pragma unroll
    for (int t = 0; t < 4; ++t) {
      int col = cg * 64 + t * 16 + l15;
      bf16x4 v;
#pragma unroll
      for (int i = 0; i < 4; ++i) v[i] = (bf16)acc[t][i];
      *(bf16x4*)(Zbt + ((long)rt * FOUT + col) * 16 + quad * 4) = v;
    }
  }
}

// ---------------- FUSED: SpMM + bias + ReLU + LN + GEMM(WT) ------------------------
// One block per block-row b (16 nodes). 4 waves; wave w owns cols [64w,64w+64) of
// the spmm output, then col-group of the FOUT GEMM output.
// h never goes to global: C-layout accs -> LN in registers -> LDS tile (A-layout
// reads) -> MFMA with WT fragments (L2-hot).
template<int FOUT>
__global__ __launch_bounds__(256) void fused_ln_gemm(const float* __restrict__ Abv,
                                                     const int*   __restrict__ Abc,
                                                     const bf16*  __restrict__ ZbtIn,
                                                     const float* __restrict__ bias,
                                                     const float* __restrict__ gamma,
                                                     const float* __restrict__ beta,
                                                     const bf16*  __restrict__ WT,
                                                     bf16* __restrict__ ZbtOut) {
  const int b    = blockIdx.x;
  const int wave = threadIdx.x >> 6;
  const int lane = threadIdx.x & 63;
  const int l15  = lane & 15;
  const int quad = lane >> 4;

  const int*   bc    = Abc + b * KNZ;
  const int    cst   = (quad & 1) * 8;
  const int    half  = quad >> 1;
  const float* abase = Abv + (long)b * (KNZ * 256) + l15 * 16 + cst;

  // ---- phase A: gather cluster (keep ALL loads outstanding) ----
  bf16x8 afr[4];
  long   zb[4];
#pragma unroll
  for (int kp = 0; kp < 4; ++kp) {
    int blk = 2 * kp + half;
    afr[kp] = load8(abase + blk * 256);
    zb[kp]  = (long)bc[blk] * (HID * 16) + cst;
  }
  bf16x8 bfr[4][4];
#pragma unroll
  for (int kp = 0; kp < 4; ++kp)
#pragma unroll
    for (int t = 0; t < 4; ++t) {
      int f = wave * 64 + t * 16 + l15;
      bfr[kp][t] = *(const bf16x8*)(ZbtIn + zb[kp] + f * 16);
    }
  __builtin_amdgcn_sched_barrier(0);   // loads stay above, MFMAs below

  f32x4 acc[4] = {};
#pragma unroll
  for (int kp = 0; kp < 4; ++kp)
#pragma unroll
    for (int t = 0; t < 4; ++t)
      acc[t] = mfma16(afr[kp], bfr[kp][t], acc[t]);

  // ---- phase B: bias + relu + LN (register partials, tiny LDS exchange) ----
  float gv[4], bv[4];
  float ps[4] = {0.f, 0.f, 0.f, 0.f}, pss[4] = {0.f, 0.f, 0.f, 0.f};
#pragma unroll
  for (int t = 0; t < 4; ++t) {
    int f = wave * 64 + t * 16 + l15;
    float bi = bias[f];
    gv[t] = gamma[f];
    bv[t] = beta[f];
#pragma unroll
    for (int i = 0; i < 4; ++i) {
      float v = acc[t][i] + bi;
      v = v > 0.f ? v : 0.f;
      acc[t][i] = v;
      ps[i] += v;
      pss[i] += v * v;
    }
  }
#pragma unroll
  for (int m = 1; m < 16; m <<= 1) {
#pragma unroll
    for (int i = 0; i < 4; ++i) {
      ps[i]  += __shfl_xor(ps[i], m, 64);
      pss[i] += __shfl_xor(pss[i], m, 64);
    }
  }
  __shared__ float S[4][16], SS[4][16];
  __shared__ bf16  hl[16][264];   // 16 rows x 256 cols, pad 264 (bank spread)
  if (l15 == 0) {
#pragma unroll
    for (int i = 0; i < 4; ++i) {
      S[wave][quad * 4 + i]  = ps[i];
      SS[wave][quad * 4 + i] = pss[i];
    }
  }
  __syncthreads();
#pragma unroll
  for (int i = 0; i < 4; ++i) {
    int r = quad * 4 + i;
    float s    = S[0][r] + S[1][r] + S[2][r] + S[3][r];
    float ss   = SS[0][r] + SS[1][r] + SS[2][r] + SS[3][r];
    float mu   = s * (1.f / 256.f);
    float var  = ss * (1.f / 256.f) - mu * mu;
    float rstd = rsqrtf(var + 1e-5f);
#pragma unroll
    for (int t = 0; t < 4; ++t) {
      int f = wave * 64 + t * 16 + l15;
      hl[r][f] = (bf16)((acc[t][i] - mu) * rstd * gv[t] + bv[t]);
    }
  }
  __syncthreads();

  // ---- phase C: GEMM h(LDS) @ W -> ZbtOut (bt layout) ----
  constexpr int TPW = FOUT / 64;          // 16-col tiles per wave (4 or 1)
  const int cb = wave * (FOUT / 4);       // wave's column base
  f32x4 acc2[TPW] = {};
#pragma unroll
  for (int k = 0; k < 8; ++k) {
    bf16x8 a = *(const bf16x8*)(&hl[l15][k * 32 + quad * 8]);
#pragma unroll
    for (int t = 0; t < TPW; ++t) {
      const bf16* wp = WT + (long)(cb + t * 16 + l15) * HID + k * 32 + quad * 8;
      acc2[t] = mfma16(a, *(const bf16x8*)wp, acc2[t]);
    }
  }
#pragma unroll
  for (int t = 0; t < TPW; ++t) {
    int col = cb + t * 16 + l15;
    bf16x4 v;
#pragma unroll
    for (int i = 0; i < 4; ++i) v[i] = (bf16)acc2[t][i];
    *(bf16x4*)(ZbtOut + ((long)b * FOUT + col) * 16 + quad * 4) = v;
  }
}

// ---------------- final SpMM + bias (F = NCLS = 64), row-major FLOAT32 out -------
__global__ __launch_bounds__(256) void spmm_out(const float* __restrict__ Abv,
                                                const int*   __restrict__ Abc,
                                                const bf16*  __restrict__ Zbt,  // [BRQ,64,16]
                                                const float* __restrict__ bias, // [64]
                                                float* __restrict__ out) {      // [N,64] f32
  const int wave = threadIdx.x >> 6;
  const int b    = blockIdx.x * 4 + wave;
  const int lane = threadIdx.x & 63;
  const int l15  = lane & 15;
  const int quad = lane >> 4;

  const int*   bc    = Abc + b * KNZ;
  const int    cst   = (quad & 1) * 8;
  const int    half  = quad >> 1;
  const float* abase = Abv + (long)b * (KNZ * 256) + l15 * 16 + cst;

  bf16x8 afr[4];
  long   zb[4];
#pragma unroll
  for (int kp = 0; kp < 4; ++kp) {
    int blk = 2 * kp + half;
    afr[kp] = load8(abase + blk * 256);
    zb[kp]  = (long)bc[blk] * (NCLS * 16) + cst;
  }
  bf16x8 bfr[4][4];
#pragma unroll
  for (int kp = 0; kp < 4; ++kp)
#pragma unroll
    for (int t = 0; t < 4; ++t) {
      int f = t * 16 + l15;
      bfr[kp][t] = *(const bf16x8*)(Zbt + zb[kp] + f * 16);
    }
  __builtin_amdgcn_sched_barrier(0);

  f32x4 acc[4] = {};
#pragma unroll
  for (int kp = 0; kp < 4; ++kp)
#pragma unroll
    for (int t = 0; t < 4; ++t)
      acc[t] = mfma16(afr[kp], bfr[kp][t], acc[t]);

#pragma unroll
  for (int t = 0; t < 4; ++t) {
    int f = t * 16 + l15;
    float bi = bias[f];
#pragma unroll
    for (int i = 0; i < 4; ++i) {
      out[(long)(b * 16 + quad * 4 + i) * NCLS + f] = acc[t][i] + bi;
    }
  }
}

extern "C" void kernel_launch(void* const* d_in, const int* in_sizes, int n_in,
                              void* d_out, int out_size, void* d_ws, size_t ws_size,
                              hipStream_t stream) {
  const float* features = (const float*)d_in[0];
  const float* bvals    = (const float*)d_in[1];
  const float* W0       = (const float*)d_in[2];
  const float* b0       = (const float*)d_in[3];
  const float* W1       = (const float*)d_in[4];
  const float* b1       = (const float*)d_in[5];
  const float* W2       = (const float*)d_in[6];
  const float* b2       = (const float*)d_in[7];
  const float* g0       = (const float*)d_in[8];
  const float* beta0    = (const float*)d_in[9];
  const float* g1       = (const float*)d_in[10];
  const float* beta1    = (const float*)d_in[11];
  const int*   bcols    = (const int*)d_in[12];
  float* outp = (float*)d_out;

  // d_ws halves ping-pong (128 MiB total):
  bf16* zbt1 = (bf16*)d_ws;                       // [N,256] bt-layout (half 1)
  bf16* zbt2 = zbt1 + (size_t)N_NODES * HID;      // [N,256] bt-layout (half 2)
  bf16* zbt3 = zbt1;                              // [N,64]  bt-layout (reuses half 1)

  // Transposed bf16 weights in d_out-as-scratch (224 KB of 33.6 MB output buffer).
  // All reads complete before spmm_out overwrites d_out (stream order).
  bf16* w0t = (bf16*)d_out;
  bf16* w1t = w0t + IN_F * HID;
  bf16* w2t = w1t + HID * HID;

  transpose_all<<<dim3(448), dim3(256), 0, stream>>>(W0, W1, W2, w0t, w1t, w2t);

  gemm_bt<float, IN_F, HID, 1024><<<dim3(1024), dim3(256), 0, stream>>>(features, w0t, zbt1);
  fused_ln_gemm<HID><<<dim3(BRQ), dim3(256), 0, stream>>>(bvals, bcols, zbt1,
                                                          b0, g0, beta0, w1t, zbt2);
  fused_ln_gemm<NCLS><<<dim3(BRQ), dim3(256), 0, stream>>>(bvals, bcols, zbt2,
                                                           b1, g1, beta1, w2t, zbt3);
  spmm_out<<<dim3(BRQ / 4), dim3(256), 0, stream>>>(bvals, bcols, zbt3, b2, outp);
}